// Round 3
// baseline (838.911 us; speedup 1.0000x reference)
//
#include <hip/hip_runtime.h>

typedef unsigned short u16;
typedef unsigned int u32;
using f32x4 = __attribute__((ext_vector_type(4))) float;
using bf16x8 = __attribute__((ext_vector_type(8))) short;

#define EPSF 1e-8f

constexpr int C1 = 768;
constexpr int HW = 9216;        // 96*96
constexpr int CJ = 2304;        // 3*768 joint channels
constexpr int BM = 128, BN = 128, BK = 32;
constexpr int NT = CJ / BK;     // 72 k-tiles
constexpr int NS = 24;          // N splits (must divide 72)
constexpr int TPS = (HW / BN) / NS; // 3 col-tiles per split

__device__ __forceinline__ u16 f2bf(float f) {
    u32 u = __float_as_uint(f);
    u += 0x7FFFu + ((u >> 16) & 1u);   // RNE
    return (u16)(u >> 16);
}
__device__ __forceinline__ float bf2f(u16 h) {
    return __uint_as_float(((u32)h) << 16);
}

// ---------------- transpose + fp32->bf16: out[j][c] = in[c][j] ----------------
__global__ void k_transpose(const float* __restrict__ s0, const float* __restrict__ s1,
                            const float* __restrict__ s2, u16* __restrict__ dst) {
    __shared__ float tile[32][33];
    const int j0 = blockIdx.x * 32;
    const int c0 = blockIdx.y * 32;
    const int tx = threadIdx.x, ty = threadIdx.y;
    // FIX (round 1): c0 & 767 != c0 % 768 (768 is not pow2; bit8 of 767 is 0) —
    // segments 1/2 read duplicated/missing channel rows. Proper segment select:
    const int seg = (c0 >= 1536) ? 2 : (c0 >= 768) ? 1 : 0;
    const float* src = (seg == 0) ? s0 : (seg == 1) ? s1 : s2;
    const int cb = c0 - seg * 768;
#pragma unroll
    for (int r = 0; r < 4; ++r) {
        int cc = ty + r * 8;
        tile[cc][tx] = src[(size_t)(cb + cc) * HW + j0 + tx];
    }
    __syncthreads();
#pragma unroll
    for (int r = 0; r < 4; ++r) {
        int jj = ty + r * 8;
        dst[(size_t)(j0 + jj) * CJ + c0 + tx] = f2bf(tile[tx][jj]);
    }
}

// ---------------- per-column squared sums + 1/(sqrt(s)+eps) for all 6 mats ----------------
__global__ void k_colsq(const float* __restrict__ p0, const float* __restrict__ p1,
                        const float* __restrict__ p2, const float* __restrict__ p3,
                        const float* __restrict__ p4, const float* __restrict__ p5,
                        float* __restrict__ sq, float* __restrict__ inv) {
    const float* src;
    switch (blockIdx.y) {
        case 0: src = p0; break; case 1: src = p1; break; case 2: src = p2; break;
        case 3: src = p3; break; case 4: src = p4; break; default: src = p5; break;
    }
    const int j = blockIdx.x * 256 + threadIdx.x;
    float s = 0.f;
#pragma unroll 8
    for (int c = 0; c < C1; ++c) {
        float v = src[(size_t)c * HW + j];
        s = fmaf(v, v, s);
    }
    sq[blockIdx.y * HW + j] = s;
    inv[blockIdx.y * HW + j] = 1.0f / (sqrtf(s) + EPSF);
}

// ---------------- joint style norm: 1/(sqrt(s1+s3+s5+EPS)+EPS) ----------------
__global__ void k_joint(const float* __restrict__ sq, float* __restrict__ invbnj) {
    const int j = blockIdx.x * 256 + threadIdx.x;
    float s = sq[1 * HW + j] + sq[3 * HW + j] + sq[5 * HW + j];
    invbnj[j] = 1.0f / (sqrtf(s + EPSF) + EPSF);
}

// ---------------- fused GEMM (G = CT^T*ST via bf16 MFMA) + per-row arg best/worst ----------------
__global__ __launch_bounds__(256) void k_gemm_arg(
    const u16* __restrict__ CT, const u16* __restrict__ ST,
    const float* __restrict__ invbn,
    float* __restrict__ bestv, int* __restrict__ besti,
    float* __restrict__ worstv, int* __restrict__ worsti) {
    __shared__ u16 ldsA[BM * BK];
    __shared__ u16 ldsB[BN * BK];
    __shared__ float s_bv[2][BM]; __shared__ int s_bi[2][BM];
    __shared__ float s_wv[2][BM]; __shared__ int s_wi[2][BM];

    const int tid = threadIdx.x;
    const int l = tid & 63;
    const int w = tid >> 6;
    const int wr = w >> 1, wc = w & 1;
    const int bx = blockIdx.x, sp = blockIdx.y;
    const int rowbase = bx * BM;

    if (tid < BM) {
        s_bv[0][tid] = -3.4e38f; s_bv[1][tid] = -3.4e38f;
        s_wv[0][tid] =  3.4e38f; s_wv[1][tid] =  3.4e38f;
        s_bi[0][tid] = 0x7fffffff; s_bi[1][tid] = 0x7fffffff;
        s_wi[0][tid] = 0x7fffffff; s_wi[1][tid] = 0x7fffffff;
    }

    // staging: thread covers rows st_r and st_r+64, 16B k-slot st_s (of 4)
    const int st_s = tid & 3;
    const int st_r = tid >> 2;                  // 0..63
    const int swz = st_s ^ ((st_r >> 1) & 3);   // XOR slot swizzle (same for r and r+64)
    const size_t aoff0 = (size_t)(rowbase + st_r) * CJ + st_s * 8;
    const size_t aoff1 = aoff0 + (size_t)64 * CJ;

    const int frow = l & 15;
    const int fk = l >> 4;
    const f32x4 fzero = {0.f, 0.f, 0.f, 0.f};

#pragma unroll 1
    for (int ct = 0; ct < TPS; ++ct) {
        const int colbase = (sp * TPS + ct) * BN;
        const size_t boff0 = (size_t)(colbase + st_r) * CJ + st_s * 8;
        const size_t boff1 = boff0 + (size_t)64 * CJ;

        f32x4 acc[4][4];
#pragma unroll
        for (int m = 0; m < 4; ++m)
#pragma unroll
            for (int n = 0; n < 4; ++n) acc[m][n] = fzero;

        bf16x8 ra0 = *(const bf16x8*)(CT + aoff0);
        bf16x8 ra1 = *(const bf16x8*)(CT + aoff1);
        bf16x8 rb0 = *(const bf16x8*)(ST + boff0);
        bf16x8 rb1 = *(const bf16x8*)(ST + boff1);

#pragma unroll 1
        for (int kt = 0; kt < NT; ++kt) {
            __syncthreads();
            *(bf16x8*)&ldsA[st_r * BK + swz * 8] = ra0;
            *(bf16x8*)&ldsA[(st_r + 64) * BK + swz * 8] = ra1;
            *(bf16x8*)&ldsB[st_r * BK + swz * 8] = rb0;
            *(bf16x8*)&ldsB[(st_r + 64) * BK + swz * 8] = rb1;
            if (kt + 1 < NT) {   // prefetch next k-tile into regs (latency hides under MFMA)
                const size_t ko = (size_t)(kt + 1) * BK;
                ra0 = *(const bf16x8*)(CT + aoff0 + ko);
                ra1 = *(const bf16x8*)(CT + aoff1 + ko);
                rb0 = *(const bf16x8*)(ST + boff0 + ko);
                rb1 = *(const bf16x8*)(ST + boff1 + ko);
            }
            __syncthreads();
            bf16x8 af[4], bfr[4];
#pragma unroll
            for (int m = 0; m < 4; ++m) {
                int row = wr * 64 + m * 16 + frow;
                int slot = fk ^ ((row >> 1) & 3);
                af[m] = *(const bf16x8*)&ldsA[row * BK + slot * 8];
            }
#pragma unroll
            for (int n = 0; n < 4; ++n) {
                int col = wc * 64 + n * 16 + frow;
                int slot = fk ^ ((col >> 1) & 3);
                bfr[n] = *(const bf16x8*)&ldsB[col * BK + slot * 8];
            }
#pragma unroll
            for (int m = 0; m < 4; ++m)
#pragma unroll
                for (int n = 0; n < 4; ++n)
                    acc[m][n] = __builtin_amdgcn_mfma_f32_16x16x32_bf16(af[m], bfr[n], acc[m][n], 0, 0, 0);
        }

        // epilogue: score = G * invbn[col]; per-row best/worst over this col-tile
        float ib[4];
#pragma unroll
        for (int n = 0; n < 4; ++n) ib[n] = invbn[colbase + wc * 64 + n * 16 + frow];

#pragma unroll
        for (int m = 0; m < 4; ++m) {
#pragma unroll
            for (int i = 0; i < 4; ++i) {
                float bv = -3.4e38f, wv = 3.4e38f; int bi = 0x7fffffff, wi = 0x7fffffff;
#pragma unroll
                for (int n = 0; n < 4; ++n) {
                    float sc = acc[m][n][i] * ib[n];
                    int ci = colbase + wc * 64 + n * 16 + frow;
                    if (sc > bv) { bv = sc; bi = ci; }
                    if (sc < wv) { wv = sc; wi = ci; }
                }
#pragma unroll
                for (int d = 1; d < 16; d <<= 1) {   // reduce the 16 lanes sharing these rows
                    float obv = __shfl_xor(bv, d); int obi = __shfl_xor(bi, d);
                    if (obv > bv || (obv == bv && obi < bi)) { bv = obv; bi = obi; }
                    float owv = __shfl_xor(wv, d); int owi = __shfl_xor(wi, d);
                    if (owv < wv || (owv == wv && owi < wi)) { wv = owv; wi = owi; }
                }
                if ((l & 15) == 0) {
                    int rl = wr * 64 + m * 16 + (l >> 4) * 4 + i;
                    if (bv > s_bv[wc][rl] || (bv == s_bv[wc][rl] && bi < s_bi[wc][rl])) { s_bv[wc][rl] = bv; s_bi[wc][rl] = bi; }
                    if (wv < s_wv[wc][rl] || (wv == s_wv[wc][rl] && wi < s_wi[wc][rl])) { s_wv[wc][rl] = wv; s_wi[wc][rl] = wi; }
                }
            }
        }
    }

    __syncthreads();
    if (tid < BM) {
        float bv = s_bv[0][tid]; int bi = s_bi[0][tid];
        if (s_bv[1][tid] > bv || (s_bv[1][tid] == bv && s_bi[1][tid] < bi)) { bv = s_bv[1][tid]; bi = s_bi[1][tid]; }
        float wv = s_wv[0][tid]; int wi = s_wi[0][tid];
        if (s_wv[1][tid] < wv || (s_wv[1][tid] == wv && s_wi[1][tid] < wi)) { wv = s_wv[1][tid]; wi = s_wi[1][tid]; }
        bestv [(size_t)sp * HW + rowbase + tid] = bv;
        besti [(size_t)sp * HW + rowbase + tid] = bi;
        worstv[(size_t)sp * HW + rowbase + tid] = wv;
        worsti[(size_t)sp * HW + rowbase + tid] = wi;
    }
}

// ---------------- final: reduce splits, gathered cosines, loss ----------------
__global__ void k_final(const u16* __restrict__ CT, const u16* __restrict__ ST,
                        const float* __restrict__ inv6,
                        const float* __restrict__ bestv, const int* __restrict__ besti,
                        const float* __restrict__ worstv, const int* __restrict__ worsti,
                        float* __restrict__ out) {
    const int w = threadIdx.x >> 6, l = threadIdx.x & 63;
    const int r = blockIdx.x * 4 + w;

    float bv = -3.4e38f, wv = 3.4e38f; int bi = 0x7fffffff, wi = 0x7fffffff;
    if (l < NS) {
        bv = bestv [(size_t)l * HW + r]; bi = besti [(size_t)l * HW + r];
        wv = worstv[(size_t)l * HW + r]; wi = worsti[(size_t)l * HW + r];
    }
#pragma unroll
    for (int d = 1; d < 64; d <<= 1) {
        float obv = __shfl_xor(bv, d); int obi = __shfl_xor(bi, d);
        if (obv > bv || (obv == bv && obi < bi)) { bv = obv; bi = obi; }
        float owv = __shfl_xor(wv, d); int owi = __shfl_xor(wi, d);
        if (owv < wv || (owv == wv && owi < wi)) { wv = owv; wi = owi; }
    }
    const int zb = bi, zw = wi;

    const u16* ar = CT + (size_t)r * CJ;
    const u16* bb = ST + (size_t)zb * CJ;
    const u16* bw = ST + (size_t)zw * CJ;
    float db[3] = {0.f, 0.f, 0.f}, dw[3] = {0.f, 0.f, 0.f};
#pragma unroll
    for (int it = 0; it < 9; ++it) {
        const int c = it * 256 + l * 4;
        uint2 va = *(const uint2*)(ar + c);
        uint2 vb = *(const uint2*)(bb + c);
        uint2 vw = *(const uint2*)(bw + c);
        const int seg = it / 3;  // 0: feats, 1: depth, 2: edge (768 = 3*256)
        float a0 = bf2f((u16)(va.x & 0xffff)), a1 = bf2f((u16)(va.x >> 16));
        float a2 = bf2f((u16)(va.y & 0xffff)), a3 = bf2f((u16)(va.y >> 16));
        float b0 = bf2f((u16)(vb.x & 0xffff)), b1 = bf2f((u16)(vb.x >> 16));
        float b2 = bf2f((u16)(vb.y & 0xffff)), b3 = bf2f((u16)(vb.y >> 16));
        float w0 = bf2f((u16)(vw.x & 0xffff)), w1 = bf2f((u16)(vw.x >> 16));
        float w2 = bf2f((u16)(vw.y & 0xffff)), w3 = bf2f((u16)(vw.y >> 16));
        db[seg] += a0 * b0 + a1 * b1 + a2 * b2 + a3 * b3;
        dw[seg] += a0 * w0 + a1 * w1 + a2 * w2 + a3 * w3;
    }
#pragma unroll
    for (int d = 1; d < 64; d <<= 1) {
#pragma unroll
        for (int s = 0; s < 3; ++s) {
            db[s] += __shfl_xor(db[s], d);
            dw[s] += __shfl_xor(dw[s], d);
        }
    }
    if (l == 0) {
        float c0 = db[0] * inv6[0 * HW + r] * inv6[1 * HW + zb];
        float c1 = db[1] * inv6[2 * HW + r] * inv6[3 * HW + zb];
        float c2 = db[2] * inv6[4 * HW + r] * inv6[5 * HW + zb];
        float d0 = dw[0] * inv6[0 * HW + r] * inv6[1 * HW + zw];
        float d1 = dw[1] * inv6[2 * HW + r] * inv6[3 * HW + zw];
        float d2 = dw[2] * inv6[4 * HW + r] * inv6[5 * HW + zw];
        float contrib = (6.0f - c0 - c1 - c2 + d0 + d1 + d2) * (1.0f / 9216.0f);
        atomicAdd(out, contrib);
    }
}

extern "C" void kernel_launch(void* const* d_in, const int* in_sizes, int n_in,
                              void* d_out, int out_size, void* d_ws, size_t ws_size,
                              hipStream_t stream) {
    const float* x  = (const float*)d_in[0];
    const float* s  = (const float*)d_in[1];
    const float* rd = (const float*)d_in[2];
    const float* sd = (const float*)d_in[3];
    const float* re = (const float*)d_in[4];
    const float* se = (const float*)d_in[5];

    char* ws = (char*)d_ws;
    const size_t SZT = (size_t)HW * CJ * 2;          // 42,467,328 B each
    u16*   CTt    = (u16*)ws;
    u16*   STt    = (u16*)(ws + SZT);
    float* sq6    = (float*)(ws + 2 * SZT);          // 6*HW floats
    float* inv6   = sq6 + 6 * HW;                    // 6*HW floats
    float* invbnj = inv6 + 6 * HW;                   // HW floats
    float* bestv  = invbnj + HW;                     // NS*HW floats
    int*   besti  = (int*)(bestv + (size_t)NS * HW);
    float* worstv = (float*)(besti + (size_t)NS * HW);
    int*   worsti = (int*)(worstv + (size_t)NS * HW);
    const size_t NEED = 2 * SZT + (size_t)(13 + 4 * NS) * HW * 4;
    if (ws_size < NEED) return;  // ws too small: fail loudly (wrong output)

    hipMemsetAsync(d_out, 0, sizeof(float), stream);

    k_transpose<<<dim3(HW / 32, CJ / 32), dim3(32, 8), 0, stream>>>(x, rd, re, CTt);
    k_transpose<<<dim3(HW / 32, CJ / 32), dim3(32, 8), 0, stream>>>(s, sd, se, STt);
    k_colsq<<<dim3(HW / 256, 6), 256, 0, stream>>>(x, s, rd, sd, re, se, sq6, inv6);
    k_joint<<<HW / 256, 256, 0, stream>>>(sq6, invbnj);
    k_gemm_arg<<<dim3(HW / BM, NS), 256, 0, stream>>>(CTt, STt, invbnj, bestv, besti, worstv, worsti);
    k_final<<<HW / 4, 256, 0, stream>>>(CTt, STt, inv6, bestv, besti, worstv, worsti, (float*)d_out);
}